// Round 2
// baseline (588.133 us; speedup 1.0000x reference)
//
#include <hip/hip_runtime.h>

#define NL 21
#define NC 256
#define NB 64
#define PSTRIDE 68   // plane row stride in floats: float4-aligned, rotates banks

// ---- fused pooling kernel: blockIdx.x = b*256+c, blockIdx.y = feature ----
__global__ __launch_bounds__(256) void pool_kernel(
    const float* __restrict__ f1, const float* __restrict__ f2,
    const float* __restrict__ pre1, const float* __restrict__ pre2,
    float* __restrict__ part1, float* __restrict__ part2) {
    const int blk = blockIdx.x;          // 0 .. 16383
    const int b = blk >> 8;
    const int c = blk & 255;
    const float* __restrict__ feat = blockIdx.y ? f2 : f1;
    const float* __restrict__ pre  = blockIdx.y ? pre2 : pre1;
    float* __restrict__ outp       = blockIdx.y ? part2 : part1;

    __shared__ float plane[64 * PSTRIDE];
    __shared__ float part[256];
    __shared__ int s_left[NL], s_right[NL], s_down[NL], s_upper[NL];
    __shared__ float s_invs[NL];

    const int t = threadIdx.x;

    // landmark bounds (faithful quirks: x -> H axis, y -> W axis; trunc casts
    // after clamp; inclusive divisor, exclusive sum)
    if (t < NL) {
        const float x = pre[(b * NL + t) * 2 + 0];
        const float y = pre[(b * NL + t) * 2 + 1];
        const int down  = (int)fmaxf(y - 6.0f, 0.0f);
        const int left  = (int)fmaxf(x - 6.0f, 0.0f);
        const int upper = (int)fminf(y + 6.0f, 63.0f);
        const int right = (int)fminf(x + 6.0f, 63.0f);
        s_left[t] = left; s_right[t] = right; s_down[t] = down; s_upper[t] = upper;
        s_invs[t] = 1.0f / (float)((upper - down + 1) * (right - left + 1));
    }

    // cooperative plane load: 4096 floats = 1024 float4, 4 per thread
    const float4* __restrict__ src =
        (const float4*)(feat + ((size_t)b * NC + c) * 4096);
#pragma unroll
    for (int k = 0; k < 4; ++k) {
        const int f = t + k * 256;       // float4 index 0..1023
        const int row = f >> 4;          // 16 float4 per row
        const int col4 = f & 15;
        const float4 v = src[f];
        float* dst = &plane[row * PSTRIDE + col4 * 4];
        dst[0] = v.x; dst[1] = v.y; dst[2] = v.z; dst[3] = v.w;
    }
    __syncthreads();

    // (landmark, row) partial sums: 21*12 = 252 active threads
    float val = 0.0f;
    if (t < NL * 12) {
        const int l = t / 12;
        const int k = t - l * 12;
        const int h = s_left[l] + k;
        if (h < s_right[l]) {
            const float* row = &plane[h * PSTRIDE];
            const int d = s_down[l], u = s_upper[l];
            float s = 0.0f;
            for (int w = d; w < u; ++w) s += row[w];
            val = s;
        }
    }
    part[t] = val;
    __syncthreads();

    // fold 12 row-partials per landmark, scale, store per-(b,l,c) partial
    if (t < NL) {
        float r = 0.0f;
#pragma unroll
        for (int k = 0; k < 12; ++k) r += part[t * 12 + k];
        outp[((size_t)b * NL + t) * NC + c] = r * s_invs[t];
    }
}

// ---------------- finish kernel: batch-reduce + EMA + log_softmax + KL ----------------
__device__ __forceinline__ float wave_sum(float v) {
#pragma unroll
    for (int o = 32; o > 0; o >>= 1) v += __shfl_xor(v, o, 64);
    return v;
}
__device__ __forceinline__ float wave_max(float v) {
#pragma unroll
    for (int o = 32; o > 0; o >>= 1) v = fmaxf(v, __shfl_xor(v, o, 64));
    return v;
}
__device__ __forceinline__ float block_sum(float v, float* red) {
    v = wave_sum(v);
    const int wave = threadIdx.x >> 6, lane = threadIdx.x & 63;
    __syncthreads();
    if (lane == 0) red[wave] = v;
    __syncthreads();
    return red[0] + red[1] + red[2] + red[3];
}
__device__ __forceinline__ float block_max(float v, float* red) {
    v = wave_max(v);
    const int wave = threadIdx.x >> 6, lane = threadIdx.x & 63;
    __syncthreads();
    if (lane == 0) red[wave] = v;
    __syncthreads();
    return fmaxf(fmaxf(red[0], red[1]), fmaxf(red[2], red[3]));
}

__global__ __launch_bounds__(256) void finish_kernel(
    const float* __restrict__ part1, const float* __restrict__ part2,
    const float* __restrict__ fea1, const float* __restrict__ fea2,
    float* __restrict__ out) {
    const int c = threadIdx.x;           // exactly 256 channels
    __shared__ float red[4];
    __shared__ float sc1[NL][NC];
    __shared__ float sc2[NL][NC];

    // batch reduction: register accumulators, fully unrolled l so they stay in VGPRs
    float a1[NL], a2[NL];
#pragma unroll
    for (int l = 0; l < NL; ++l) { a1[l] = 0.0f; a2[l] = 0.0f; }
    for (int b = 0; b < NB; ++b) {
#pragma unroll
        for (int l = 0; l < NL; ++l) {
            a1[l] += part1[((size_t)b * NL + l) * NC + c];
            a2[l] += part2[((size_t)b * NL + l) * NC + c];
        }
    }
#pragma unroll
    for (int l = 0; l < NL; ++l) {
        sc1[l][c] = 0.999f * (a1[l] * (1.0f / 64.0f)) + 0.001f * fea1[l * NC + c];
        sc2[l][c] = 0.999f * (a2[l] * (1.0f / 64.0f)) + 0.001f * fea2[l * NC + c];
    }
    __syncthreads();

    double total = 0.0;
    for (int l = 0; l < NL; ++l) {
        const float x1 = sc1[l][c];
        const float x2 = sc2[l][c];

        // log_softmax of row l of fea_c1
        const float m = block_max(x1, red);
        const float e = __expf(x1 - m);
        const float se = block_sum(e, red);
        const float logZ = m + logf(se);
        const float logp = x1 - logZ;

        // q = fea_c2 / rowsum
        const float ssum = block_sum(x2, red);
        const float q = x2 / ssum;

        const float kl = (q > 0.0f) ? q * (logf(q) - logp) : 0.0f;
        total += (double)block_sum(kl, red);
    }
    if (c == 0) out[0] = (float)(total / 21.0);
}

extern "C" void kernel_launch(void* const* d_in, const int* in_sizes, int n_in,
                              void* d_out, int out_size, void* d_ws, size_t ws_size,
                              hipStream_t stream) {
    const float* f1   = (const float*)d_in[0];
    const float* f2   = (const float*)d_in[1];
    const float* pre1 = (const float*)d_in[2];
    const float* pre2 = (const float*)d_in[3];
    const float* fea1 = (const float*)d_in[4];
    const float* fea2 = (const float*)d_in[5];
    float* out = (float*)d_out;

    float* part1 = (float*)d_ws;                       // [64][21][256]
    float* part2 = part1 + (size_t)NB * NL * NC;       // [64][21][256]

    pool_kernel<<<dim3(NB * NC, 2), 256, 0, stream>>>(f1, f2, pre1, pre2, part1, part2);
    finish_kernel<<<1, 256, 0, stream>>>(part1, part2, fea1, fea2, out);
}

// Round 3
// 525.925 us; speedup vs baseline: 1.1183x; 1.1183x over previous
//
#include <hip/hip_runtime.h>

#define NL 21
#define NC 256
#define NB 64
#define PSTRIDE 68   // plane row stride in floats: float4-aligned (17 float4), rotates banks
#define PPB 16       // planes per block (consecutive c, same (feat,b) since 16|256)

// ---- persistent pipelined pooling kernel ----
// grid.x = 2*64*256/PPB = 2048 blocks; each handles PPB consecutive planes.
__global__ __launch_bounds__(256) void pool_kernel(
    const float* __restrict__ f1, const float* __restrict__ f2,
    const float* __restrict__ pre1, const float* __restrict__ pre2,
    float* __restrict__ part1, float* __restrict__ part2) {
    const int p0   = blockIdx.x * PPB;       // first plane id
    const int feat = p0 >> 14;               // 16384 planes per feature
    const int b    = (p0 >> 8) & 63;
    const int c0   = p0 & 255;
    const float* __restrict__ base = (feat ? f2 : f1) + (size_t)(b * NC + c0) * 4096;
    const float* __restrict__ pre  = feat ? pre2 : pre1;
    float* __restrict__ outp       = (feat ? part2 : part1) + (size_t)b * NL * NC;

    __shared__ float buf[2][64 * PSTRIDE];
    __shared__ float fold[256];
    __shared__ int s_left[NL], s_right[NL], s_down[NL], s_upper[NL];
    __shared__ float s_invs[NL];

    const int t = threadIdx.x;

    // landmark bounds, once per block (faithful quirks: x -> H axis, y -> W axis;
    // trunc casts after clamp; inclusive divisor, exclusive sum)
    if (t < NL) {
        const float x = pre[(b * NL + t) * 2 + 0];
        const float y = pre[(b * NL + t) * 2 + 1];
        const int down  = (int)fmaxf(y - 6.0f, 0.0f);
        const int left  = (int)fmaxf(x - 6.0f, 0.0f);
        const int upper = (int)fminf(y + 6.0f, 63.0f);
        const int right = (int)fminf(x + 6.0f, 63.0f);
        s_left[t] = left; s_right[t] = right; s_down[t] = down; s_upper[t] = upper;
        s_invs[t] = 1.0f / (float)((upper - down + 1) * (right - left + 1));
    }

    // prologue: load plane 0 and stage it
    float4 v0, v1, v2, v3;
    {
        const float4* __restrict__ src = (const float4*)base;
        v0 = src[t]; v1 = src[t + 256]; v2 = src[t + 512]; v3 = src[t + 768];
    }
    {
        float* d = buf[0];
        // float4 index f = t + j*256; row = f>>4 (16 float4/row), col4 = f&15
        *(float4*)&d[((t        ) >> 4) * PSTRIDE + ((t        ) & 15) * 4] = v0;
        *(float4*)&d[((t + 256) >> 4) * PSTRIDE + ((t + 256) & 15) * 4] = v1;
        *(float4*)&d[((t + 512) >> 4) * PSTRIDE + ((t + 512) & 15) * 4] = v2;
        *(float4*)&d[((t + 768) >> 4) * PSTRIDE + ((t + 768) & 15) * 4] = v3;
    }
    __syncthreads();

    for (int i = 0; i < PPB; ++i) {
        const int cur = i & 1;
        // prefetch next plane into registers (vmcnt wait lands at the ds_write below)
        if (i + 1 < PPB) {
            const float4* __restrict__ src = (const float4*)(base + (size_t)(i + 1) * 4096);
            v0 = src[t]; v1 = src[t + 256]; v2 = src[t + 512]; v3 = src[t + 768];
        }
        // (landmark, row) partial sums: 21*12 = 252 active threads
        float val = 0.0f;
        if (t < NL * 12) {
            const int l = t / 12;
            const int kk = t - l * 12;
            const int h = s_left[l] + kk;
            if (h < s_right[l]) {
                const float* row = &buf[cur][h * PSTRIDE];
                const int d = s_down[l], u = s_upper[l];
                float s = 0.0f;
                for (int w = d; w < u; ++w) s += row[w];
                val = s;
            }
        }
        fold[t] = val;
        __syncthreads();
        if (t < NL) {
            float r = 0.0f;
#pragma unroll
            for (int kk = 0; kk < 12; ++kk) r += fold[t * 12 + kk];
            outp[t * NC + (c0 + i)] = r * s_invs[t];
        }
        // stage next plane into the other buffer
        if (i + 1 < PPB) {
            float* d = buf[1 - cur];
            *(float4*)&d[((t        ) >> 4) * PSTRIDE + ((t        ) & 15) * 4] = v0;
            *(float4*)&d[((t + 256) >> 4) * PSTRIDE + ((t + 256) & 15) * 4] = v1;
            *(float4*)&d[((t + 512) >> 4) * PSTRIDE + ((t + 512) & 15) * 4] = v2;
            *(float4*)&d[((t + 768) >> 4) * PSTRIDE + ((t + 768) & 15) * 4] = v3;
        }
        __syncthreads();
    }
}

// ---- reduce kernel: [64][21][256] -> [21][256] + EMA, per feature ----
// grid.x = 2*21 = 42 blocks, 256 threads
__global__ __launch_bounds__(256) void reduce_kernel(
    const float* __restrict__ part1, const float* __restrict__ part2,
    const float* __restrict__ fea1, const float* __restrict__ fea2,
    float* __restrict__ sc /* [2][21][256] */) {
    const int f = blockIdx.x / NL;
    const int l = blockIdx.x - f * NL;
    const int c = threadIdx.x;
    const float* __restrict__ part = f ? part2 : part1;
    const float* __restrict__ fea  = f ? fea2 : fea1;
    float s = 0.0f;
    for (int b = 0; b < NB; ++b) s += part[((size_t)b * NL + l) * NC + c];
    sc[(f * NL + l) * NC + c] = 0.999f * (s * (1.0f / 64.0f)) + 0.001f * fea[l * NC + c];
}

// ---- finish kernel: one wave per row, shuffle-only reductions ----
__global__ __launch_bounds__(256) void finish_kernel(const float* __restrict__ sc,
                                                     float* __restrict__ out) {
    const int t = threadIdx.x;
    const int wave = t >> 6, lane = t & 63;
    __shared__ float rowkl[NL];

    for (int l = wave; l < NL; l += 4) {
        const float* __restrict__ r1 = &sc[l * NC];            // fea_c1 row
        const float* __restrict__ r2 = &sc[(NL + l) * NC];     // fea_c2 row
        float x1[4], x2[4];
#pragma unroll
        for (int j = 0; j < 4; ++j) { x1[j] = r1[lane + 64 * j]; x2[j] = r2[lane + 64 * j]; }

        float m  = fmaxf(fmaxf(x1[0], x1[1]), fmaxf(x1[2], x1[3]));
        float s2 = x2[0] + x2[1] + x2[2] + x2[3];
#pragma unroll
        for (int o = 32; o > 0; o >>= 1) {
            m  = fmaxf(m, __shfl_xor(m, o, 64));
            s2 += __shfl_xor(s2, o, 64);
        }
        float es = 0.0f;
#pragma unroll
        for (int j = 0; j < 4; ++j) es += __expf(x1[j] - m);
#pragma unroll
        for (int o = 32; o > 0; o >>= 1) es += __shfl_xor(es, o, 64);
        const float logZ = m + logf(es);
        const float inv_s2 = 1.0f / s2;

        float kl = 0.0f;
#pragma unroll
        for (int j = 0; j < 4; ++j) {
            const float q = x2[j] * inv_s2;
            if (q > 0.0f) kl += q * (logf(q) - (x1[j] - logZ));
        }
#pragma unroll
        for (int o = 32; o > 0; o >>= 1) kl += __shfl_xor(kl, o, 64);
        if (lane == 0) rowkl[l] = kl;
    }
    __syncthreads();
    if (t == 0) {
        float tot = 0.0f;
        for (int l = 0; l < NL; ++l) tot += rowkl[l];
        out[0] = tot / 21.0f;
    }
}

extern "C" void kernel_launch(void* const* d_in, const int* in_sizes, int n_in,
                              void* d_out, int out_size, void* d_ws, size_t ws_size,
                              hipStream_t stream) {
    const float* f1   = (const float*)d_in[0];
    const float* f2   = (const float*)d_in[1];
    const float* pre1 = (const float*)d_in[2];
    const float* pre2 = (const float*)d_in[3];
    const float* fea1 = (const float*)d_in[4];
    const float* fea2 = (const float*)d_in[5];
    float* out = (float*)d_out;

    float* part1 = (float*)d_ws;                       // [64][21][256]
    float* part2 = part1 + (size_t)NB * NL * NC;       // [64][21][256]
    float* sc    = part2 + (size_t)NB * NL * NC;       // [2][21][256]

    pool_kernel<<<dim3(2 * NB * NC / PPB), 256, 0, stream>>>(f1, f2, pre1, pre2, part1, part2);
    reduce_kernel<<<dim3(2 * NL), 256, 0, stream>>>(part1, part2, fea1, fea2, sc);
    finish_kernel<<<1, 256, 0, stream>>>(sc, out);
}